// Round 1
// baseline (34.875 us; speedup 1.0000x reference)
//
#include <hip/hip_runtime.h>

#define N_NODES 100000
#define N_EDGES 1600000

// ws layout (floats): [0..255] wfold = W1@W2 ; [256] c = b1.W2 + b2 ;
// int at word [257]: flag (1 => edges are int64) ; [512..] s_src[N] ; then s_dst[N]

__global__ void prep_kernel(const float* __restrict__ W1, const float* __restrict__ b1,
                            const float* __restrict__ W2, const float* __restrict__ b2,
                            const int* __restrict__ edges32,
                            float* __restrict__ wf, float* __restrict__ cflag) {
    int t = threadIdx.x;  // 256 threads
    float acc = 0.f;
#pragma unroll
    for (int k = 0; k < 16; ++k) acc += W1[t * 16 + k] * W2[k];
    wf[t] = acc;

    __shared__ int nz;
    if (t == 0) nz = 0;
    __syncthreads();
    // sample 256 odd words of edges; for int64 (le) these are high words == 0
    if (edges32[2 * t + 1] != 0) atomicAdd(&nz, 1);
    __syncthreads();
    if (t == 0) {
        float c = b2[0];
#pragma unroll
        for (int k = 0; k < 16; ++k) c += b1[k] * W2[k];
        cflag[0] = c;
        ((int*)cflag)[1] = (nz == 0) ? 1 : 0;
    }
}

// one node per 16-lane group; float4 loads cover the 64-float row exactly
__global__ void node_kernel(const float* __restrict__ h1, const float* __restrict__ h2,
                            const float* __restrict__ wf,
                            float* __restrict__ ssrc, float* __restrict__ sdst) {
    const int li = threadIdx.x & 15;
    const int g  = threadIdx.x >> 4;
    const int node = blockIdx.x * 16 + g;   // grid sized exactly: 6250*16 = 100000

    const float4* wf4 = (const float4*)wf;
    const float4 ws1 = wf4[li];        // w[0:64)   pairs h1 (src half)
    const float4 ws2 = wf4[16 + li];   // w[64:128) pairs h2 (src half)
    const float4 wd1 = wf4[32 + li];   // w[128:192) pairs h1 (dst half)
    const float4 wd2 = wf4[48 + li];   // w[192:256) pairs h2 (dst half)

    const float4 a = ((const float4*)(h1 + (size_t)node * 64))[li];
    const float4 b = ((const float4*)(h2 + (size_t)node * 64))[li];

    float ps = a.x * ws1.x + a.y * ws1.y + a.z * ws1.z + a.w * ws1.w
             + b.x * ws2.x + b.y * ws2.y + b.z * ws2.z + b.w * ws2.w;
    float pd = a.x * wd1.x + a.y * wd1.y + a.z * wd1.z + a.w * wd1.w
             + b.x * wd2.x + b.y * wd2.y + b.z * wd2.z + b.w * wd2.w;

#pragma unroll
    for (int off = 1; off < 16; off <<= 1) {   // reduce within 16-lane group
        ps += __shfl_xor(ps, off);
        pd += __shfl_xor(pd, off);
    }
    if (li == 0) { ssrc[node] = ps; sdst[node] = pd; }
}

__global__ void edge_kernel(const void* __restrict__ edges,
                            const float* __restrict__ ssrc, const float* __restrict__ sdst,
                            const float* __restrict__ cflag,
                            float* __restrict__ out) {
    const int e = blockIdx.x * blockDim.x + threadIdx.x;  // 6250*256 = 1.6M exact
    const float c = cflag[0];
    const int is64 = ((const int*)cflag)[1];
    int s, d;
    if (is64) {
        const long long* e64 = (const long long*)edges;
        s = (int)e64[e];
        d = (int)e64[N_EDGES + e];
    } else {
        const int* e32 = (const int*)edges;
        s = e32[e];
        d = e32[N_EDGES + e];
    }
    out[e] = ssrc[s] + sdst[d] + c;
}

extern "C" void kernel_launch(void* const* d_in, const int* in_sizes, int n_in,
                              void* d_out, int out_size, void* d_ws, size_t ws_size,
                              hipStream_t stream) {
    const float* h1 = (const float*)d_in[0];
    const float* h2 = (const float*)d_in[1];
    const float* W1 = (const float*)d_in[2];
    const float* b1 = (const float*)d_in[3];
    const float* W2 = (const float*)d_in[4];
    const float* b2 = (const float*)d_in[5];
    const void*  edges = d_in[6];

    float* wsf   = (float*)d_ws;
    float* wf    = wsf;            // 256 floats
    float* cflag = wsf + 256;      // c + int flag
    float* ssrc  = wsf + 512;      // N_NODES floats
    float* sdst  = wsf + 512 + N_NODES;
    float* out   = (float*)d_out;

    prep_kernel<<<1, 256, 0, stream>>>(W1, b1, W2, b2, (const int*)edges, wf, cflag);
    node_kernel<<<N_NODES / 16, 256, 0, stream>>>(h1, h2, wf, ssrc, sdst);
    edge_kernel<<<N_EDGES / 256, 256, 0, stream>>>(edges, ssrc, sdst, cflag, out);
}